// Round 3
// baseline (470.460 us; speedup 1.0000x reference)
//
#include <hip/hip_runtime.h>

#define N_TOK 8192
#define DIM   512
#define NREL  20
#define NGRP  40   // 2R
#define OUTD  256
#define BM 64
#define BN 64
#define BK 64
#define LPAD 8     // pad (in u16) -> row stride 144B, breaks 32-way bank conflict

typedef unsigned short u16;
typedef u16    u16x8  __attribute__((ext_vector_type(8)));
typedef u16    u16x4  __attribute__((ext_vector_type(4)));
typedef __bf16 bf16x8 __attribute__((ext_vector_type(8)));
typedef float  f32x4  __attribute__((ext_vector_type(4)));

__device__ __forceinline__ u16 f2bf(float f) {
  union { float f; unsigned u; } v; v.f = f;
  return (u16)((v.u + 0x7FFFu + ((v.u >> 16) & 1u)) >> 16);  // RNE
}

// fp32 -> bf16 (optionally fused ReLU), vectorized float4 -> 4x bf16
__global__ void k_cvt(const float* __restrict__ in, u16* __restrict__ out,
                      int n4, int relu) {
  int stride = gridDim.x * blockDim.x;
  for (int idx = blockIdx.x * blockDim.x + threadIdx.x; idx < n4; idx += stride) {
    float4 v = reinterpret_cast<const float4*>(in)[idx];
    if (relu) {
      v.x = fmaxf(v.x, 0.f); v.y = fmaxf(v.y, 0.f);
      v.z = fmaxf(v.z, 0.f); v.w = fmaxf(v.w, 0.f);
    }
    u16x4 o = { f2bf(v.x), f2bf(v.y), f2bf(v.z), f2bf(v.w) };
    reinterpret_cast<u16x4*>(out)[idx] = o;
  }
}

// ---- edge bucketing by relation ----
__global__ void k_hist(const int* __restrict__ rel, int* __restrict__ cnt) {
  int e = blockIdx.x * blockDim.x + threadIdx.x;
  if (e < N_TOK) atomicAdd(&cnt[rel[e]], 1);
}
__global__ void k_scan(const int* __restrict__ cnt, int* __restrict__ off) {
  if (threadIdx.x == 0) {
    int s = 0;
    for (int r = 0; r < NREL; ++r) { off[r] = s; s += cnt[r]; }
    off[NREL] = s;
  }
}
__global__ void k_fill(const int* __restrict__ rel, const int* __restrict__ off,
                       int* __restrict__ cur, int* __restrict__ elist) {
  int e = blockIdx.x * blockDim.x + threadIdx.x;
  if (e < N_TOK) {
    int r = rel[e];
    int p = atomicAdd(&cur[r], 1);
    elist[off[r] + p] = e;
  }
}

// ---- dense GEMM: C[M,Nn] = A(bf16)[M,512] @ W(bf16)[Nn,512]^T + bias ----
__global__ __launch_bounds__(256) void k_gemm(
    const u16* __restrict__ A, const u16* __restrict__ W,
    const float* __restrict__ bias, float* __restrict__ C,
    int M, int Nn)
{
  __shared__ u16 As[BM][BK + LPAD];
  __shared__ u16 Bs[BN][BK + LPAD];
  const int m0 = blockIdx.x * BM, n0 = blockIdx.y * BN;
  const int t = threadIdx.x;
  const int w = t >> 6, l = t & 63;
  const int wr = (w >> 1) * 32, wc = (w & 1) * 32;   // wave tile origin in 64x64
  const int lc = l & 15, lk = (l >> 4) * 8;          // fragment row/col + k slot
  const int srow = t >> 2, scol = (t & 3) * 16;      // staging: 4 thr/row, 16 u16 each

  f32x4 acc[2][2] = {};
  const u16* gA = A + (size_t)(m0 + srow) * DIM + scol;
  const u16* gB = W + (size_t)(n0 + srow) * DIM + scol;

  for (int k0 = 0; k0 < DIM; k0 += BK) {
    *reinterpret_cast<u16x8*>(&As[srow][scol])     = *reinterpret_cast<const u16x8*>(gA + k0);
    *reinterpret_cast<u16x8*>(&As[srow][scol + 8]) = *reinterpret_cast<const u16x8*>(gA + k0 + 8);
    *reinterpret_cast<u16x8*>(&Bs[srow][scol])     = *reinterpret_cast<const u16x8*>(gB + k0);
    *reinterpret_cast<u16x8*>(&Bs[srow][scol + 8]) = *reinterpret_cast<const u16x8*>(gB + k0 + 8);
    __syncthreads();
#pragma unroll
    for (int ks = 0; ks < BK; ks += 32) {
      bf16x8 a0 = *reinterpret_cast<const bf16x8*>(&As[wr      + lc][ks + lk]);
      bf16x8 a1 = *reinterpret_cast<const bf16x8*>(&As[wr + 16 + lc][ks + lk]);
      bf16x8 b0 = *reinterpret_cast<const bf16x8*>(&Bs[wc      + lc][ks + lk]);
      bf16x8 b1 = *reinterpret_cast<const bf16x8*>(&Bs[wc + 16 + lc][ks + lk]);
      acc[0][0] = __builtin_amdgcn_mfma_f32_16x16x32_bf16(a0, b0, acc[0][0], 0, 0, 0);
      acc[0][1] = __builtin_amdgcn_mfma_f32_16x16x32_bf16(a0, b1, acc[0][1], 0, 0, 0);
      acc[1][0] = __builtin_amdgcn_mfma_f32_16x16x32_bf16(a1, b0, acc[1][0], 0, 0, 0);
      acc[1][1] = __builtin_amdgcn_mfma_f32_16x16x32_bf16(a1, b1, acc[1][1], 0, 0, 0);
    }
    __syncthreads();
  }
  // C/D layout (verified): col = lane&15, row = (lane>>4)*4 + reg
#pragma unroll
  for (int fi = 0; fi < 2; ++fi)
#pragma unroll
    for (int fj = 0; fj < 2; ++fj) {
      const int col = n0 + wc + fj * 16 + lc;
      const float bv = bias[col];
      const int rbase = m0 + wr + fi * 16 + (l >> 4) * 4;
#pragma unroll
      for (int j = 0; j < 4; ++j)
        C[(size_t)(rbase + j) * Nn + col] = acc[fi][fj][j] + bv;
    }
}

// ---- grouped edge GEMM: for group g, gather h[src] rows, GEMM with W_rel,
//      scatter-add (+bias per edge) into out[dst] ----
__global__ __launch_bounds__(256) void k_edge(
    const u16* __restrict__ h, const u16* __restrict__ Wrel,
    const float* __restrict__ brel,
    const int* __restrict__ dep, const int* __restrict__ gov,
    const int* __restrict__ elist, const int* __restrict__ off,
    float* __restrict__ out)
{
  const int g = blockIdx.y;                 // 0..39
  const int r = (g < NREL) ? g : g - NREL;
  const int base = off[r];
  const int cnt  = off[r + 1] - base;
  const int m0 = blockIdx.x * BM;
  if (m0 >= cnt) return;
  const int n0 = blockIdx.z * BN;
  const bool fwd = (g < NREL);
  const int wsel = fwd ? r : NREL + r;
  const int* gsrc = fwd ? gov : dep;
  const int* gdst = fwd ? dep : gov;

  __shared__ u16 As[BM][BK + LPAD];
  __shared__ u16 Bs[BN][BK + LPAD];
  __shared__ int s_dst[BM];
  __shared__ int s_src[BM];

  const int t = threadIdx.x;
  const int mcnt = min(BM, cnt - m0);
  if (t < BM) {
    if (t < mcnt) {
      int e = elist[base + m0 + t];
      s_src[t] = gsrc[e];
      s_dst[t] = gdst[e];
    } else { s_src[t] = -1; s_dst[t] = -1; }
  }
  __syncthreads();

  const int w = t >> 6, l = t & 63;
  const int wr = (w >> 1) * 32, wc = (w & 1) * 32;
  const int lc = l & 15, lk = (l >> 4) * 8;
  const int srow = t >> 2, scol = (t & 3) * 16;

  const u16* Wg = Wrel + (size_t)wsel * DIM * DIM;
  const int arow = (srow < mcnt) ? s_src[srow] : -1;
  const u16* gA = (arow >= 0) ? (h + (size_t)arow * DIM + scol) : nullptr;
  const u16* gB = Wg + (size_t)(n0 + srow) * DIM + scol;

  f32x4 acc[2][2] = {};

  for (int k0 = 0; k0 < DIM; k0 += BK) {
    if (arow >= 0) {
      *reinterpret_cast<u16x8*>(&As[srow][scol])     = *reinterpret_cast<const u16x8*>(gA + k0);
      *reinterpret_cast<u16x8*>(&As[srow][scol + 8]) = *reinterpret_cast<const u16x8*>(gA + k0 + 8);
    } else {
      u16x8 z = {0,0,0,0,0,0,0,0};
      *reinterpret_cast<u16x8*>(&As[srow][scol]) = z;
      *reinterpret_cast<u16x8*>(&As[srow][scol + 8]) = z;
    }
    *reinterpret_cast<u16x8*>(&Bs[srow][scol])     = *reinterpret_cast<const u16x8*>(gB + k0);
    *reinterpret_cast<u16x8*>(&Bs[srow][scol + 8]) = *reinterpret_cast<const u16x8*>(gB + k0 + 8);
    __syncthreads();
#pragma unroll
    for (int ks = 0; ks < BK; ks += 32) {
      bf16x8 a0 = *reinterpret_cast<const bf16x8*>(&As[wr      + lc][ks + lk]);
      bf16x8 a1 = *reinterpret_cast<const bf16x8*>(&As[wr + 16 + lc][ks + lk]);
      bf16x8 b0 = *reinterpret_cast<const bf16x8*>(&Bs[wc      + lc][ks + lk]);
      bf16x8 b1 = *reinterpret_cast<const bf16x8*>(&Bs[wc + 16 + lc][ks + lk]);
      acc[0][0] = __builtin_amdgcn_mfma_f32_16x16x32_bf16(a0, b0, acc[0][0], 0, 0, 0);
      acc[0][1] = __builtin_amdgcn_mfma_f32_16x16x32_bf16(a0, b1, acc[0][1], 0, 0, 0);
      acc[1][0] = __builtin_amdgcn_mfma_f32_16x16x32_bf16(a1, b0, acc[1][0], 0, 0, 0);
      acc[1][1] = __builtin_amdgcn_mfma_f32_16x16x32_bf16(a1, b1, acc[1][1], 0, 0, 0);
    }
    __syncthreads();
  }

#pragma unroll
  for (int fi = 0; fi < 2; ++fi)
#pragma unroll
    for (int fj = 0; fj < 2; ++fj) {
      const int col = n0 + wc + fj * 16 + lc;
      const float bv = brel[(size_t)wsel * DIM + col];
      const int rbase = wr + fi * 16 + (l >> 4) * 4;
#pragma unroll
      for (int j = 0; j < 4; ++j) {
        const int mrow = rbase + j;
        if (mrow < mcnt) {
          const int dst = s_dst[mrow];
          unsafeAtomicAdd(&out[(size_t)dst * DIM + col], acc[fi][fj][j] + bv);
        }
      }
    }
}

extern "C" void kernel_launch(void* const* d_in, const int* in_sizes, int n_in,
                              void* d_out, int out_size, void* d_ws, size_t ws_size,
                              hipStream_t stream) {
  const float* x      = (const float*)d_in[0];
  const int*   dep    = (const int*)d_in[1];
  const int*   rel    = (const int*)d_in[2];
  const int*   gov    = (const int*)d_in[3];
  const float* W_self = (const float*)d_in[4];
  const float* b_self = (const float*)d_in[5];
  const float* W_rel  = (const float*)d_in[6];
  const float* b_rel  = (const float*)d_in[7];
  const float* W_ff   = (const float*)d_in[8];
  const float* b_ff   = (const float*)d_in[9];
  float* out = (float*)d_out;

  char* ws = (char*)d_ws;
  size_t o = 0;
  auto alloc = [&](size_t bytes) -> void* {
    void* p = ws + o;
    o = (o + bytes + 255) & ~(size_t)255;
    return p;
  };
  u16*   Wrel_bf  = (u16*)alloc((size_t)2 * NGRP * DIM * DIM * 2);
  u16*   Wself_bf = (u16*)alloc((size_t)2 * DIM * DIM * 2);
  u16*   Wff_bf   = (u16*)alloc((size_t)OUTD * DIM * 2);
  u16*   hbuf     = (u16*)alloc((size_t)N_TOK * DIM * 2);
  float* outf     = (float*)alloc((size_t)N_TOK * DIM * 4);
  int*   cnt      = (int*)alloc(NREL * 4);
  int*   offs     = (int*)alloc((NREL + 1) * 4);
  int*   cur      = (int*)alloc(NREL * 4);
  int*   elist    = (int*)alloc(N_TOK * 4);
  (void)ws_size; (void)in_sizes; (void)n_in; (void)out_size;

  // weights -> bf16
  k_cvt<<<2048, 256, 0, stream>>>(W_rel,  Wrel_bf,  2 * NGRP * DIM * DIM / 4, 0);
  k_cvt<<<512,  256, 0, stream>>>(W_self, Wself_bf, 2 * DIM * DIM / 4, 0);
  k_cvt<<<128,  256, 0, stream>>>(W_ff,   Wff_bf,   OUTD * DIM / 4, 0);

  // bucket edges by relation
  hipMemsetAsync(cnt, 0, NREL * 4, stream);
  hipMemsetAsync(cur, 0, NREL * 4, stream);
  k_hist<<<N_TOK / 256, 256, 0, stream>>>(rel, cnt);
  k_scan<<<1, 64, 0, stream>>>(cnt, offs);
  k_fill<<<N_TOK / 256, 256, 0, stream>>>(rel, offs, cur, elist);

  // h0 = bf16(x)
  k_cvt<<<2048, 256, 0, stream>>>(x, hbuf, N_TOK * DIM / 4, 0);

  for (int l = 0; l < 2; ++l) {
    const u16*   Ws = Wself_bf + (size_t)l * DIM * DIM;
    const float* bs = b_self + (size_t)l * DIM;
    const u16*   Wr = Wrel_bf + (size_t)l * NGRP * DIM * DIM;
    const float* br = b_rel + (size_t)l * NGRP * DIM;

    dim3 g1(N_TOK / BM, DIM / BN);
    k_gemm<<<g1, 256, 0, stream>>>(hbuf, Ws, bs, outf, N_TOK, DIM);

    dim3 g2(32, NGRP, DIM / BN);   // 32 m-tiles covers up to 2048 edges/bucket (~410 actual)
    k_edge<<<g2, 256, 0, stream>>>(hbuf, Wr, br, dep, gov, elist, offs, outf);

    // h_{l+1} = bf16(relu(out))
    k_cvt<<<2048, 256, 0, stream>>>(outf, hbuf, N_TOK * DIM / 4, 1);
  }

  dim3 g3(N_TOK / BM, OUTD / BN);
  k_gemm<<<g3, 256, 0, stream>>>(hbuf, Wff_bf, b_ff, out, N_TOK, OUTD);
}

// Round 4
// 383.862 us; speedup vs baseline: 1.2256x; 1.2256x over previous
//
#include <hip/hip_runtime.h>

#define N_TOK 8192
#define DIM   512
#define NREL  20
#define NGRP  40   // 2R
#define OUTD  256
#define BM 64
#define BN 64
#define BK 64
#define LPAD 8     // pad (in u16) -> 16B-aligned rows, reduces bank conflict

typedef unsigned short u16;
typedef u16    u16x8  __attribute__((ext_vector_type(8)));
typedef u16    u16x4  __attribute__((ext_vector_type(4)));
typedef __bf16 bf16x8 __attribute__((ext_vector_type(8)));
typedef float  f32x4  __attribute__((ext_vector_type(4)));

__device__ __forceinline__ u16 f2bf(float f) {
  union { float f; unsigned u; } v; v.f = f;
  return (u16)((v.u + 0x7FFFu + ((v.u >> 16) & 1u)) >> 16);  // RNE
}

// fp32 -> bf16 (optionally fused ReLU), vectorized float4 -> 4x bf16
__global__ void k_cvt(const float* __restrict__ in, u16* __restrict__ out,
                      int n4, int relu) {
  int stride = gridDim.x * blockDim.x;
  for (int idx = blockIdx.x * blockDim.x + threadIdx.x; idx < n4; idx += stride) {
    float4 v = reinterpret_cast<const float4*>(in)[idx];
    if (relu) {
      v.x = fmaxf(v.x, 0.f); v.y = fmaxf(v.y, 0.f);
      v.z = fmaxf(v.z, 0.f); v.w = fmaxf(v.w, 0.f);
    }
    u16x4 o = { f2bf(v.x), f2bf(v.y), f2bf(v.z), f2bf(v.w) };
    reinterpret_cast<u16x4*>(out)[idx] = o;
  }
}

// ---- edge bucketing by relation ----
__global__ void k_hist(const int* __restrict__ rel, int* __restrict__ cnt) {
  int e = blockIdx.x * blockDim.x + threadIdx.x;
  if (e < N_TOK) atomicAdd(&cnt[rel[e]], 1);
}
__global__ void k_scan(const int* __restrict__ cnt, int* __restrict__ off) {
  if (threadIdx.x == 0) {
    int s = 0;
    for (int r = 0; r < NREL; ++r) { off[r] = s; s += cnt[r]; }
    off[NREL] = s;
  }
}
__global__ void k_fill(const int* __restrict__ rel, const int* __restrict__ off,
                       int* __restrict__ cur, int* __restrict__ elist) {
  int e = blockIdx.x * blockDim.x + threadIdx.x;
  if (e < N_TOK) {
    int r = rel[e];
    int p = atomicAdd(&cur[r], 1);
    elist[off[r] + p] = e;
  }
}

// ---- dense GEMM: C[M,Nn] = A(bf16)[M,512] @ W(bf16)[Nn,512]^T + bias ----
__global__ __launch_bounds__(256) void k_gemm(
    const u16* __restrict__ A, const u16* __restrict__ W,
    const float* __restrict__ bias, float* __restrict__ C,
    int M, int Nn)
{
  __shared__ u16 As[BM][BK + LPAD];
  __shared__ u16 Bs[BN][BK + LPAD];
  const int m0 = blockIdx.x * BM, n0 = blockIdx.y * BN;
  const int t = threadIdx.x;
  const int w = t >> 6, l = t & 63;
  const int wr = (w >> 1) * 32, wc = (w & 1) * 32;   // wave tile origin in 64x64
  const int lc = l & 15, lk = (l >> 4) * 8;          // fragment row/col + k slot
  const int srow = t >> 2, scol = (t & 3) * 16;      // staging: 4 thr/row, 16 u16 each

  f32x4 acc[2][2] = {};
  const u16* gA = A + (size_t)(m0 + srow) * DIM + scol;
  const u16* gB = W + (size_t)(n0 + srow) * DIM + scol;

  for (int k0 = 0; k0 < DIM; k0 += BK) {
    *reinterpret_cast<u16x8*>(&As[srow][scol])     = *reinterpret_cast<const u16x8*>(gA + k0);
    *reinterpret_cast<u16x8*>(&As[srow][scol + 8]) = *reinterpret_cast<const u16x8*>(gA + k0 + 8);
    *reinterpret_cast<u16x8*>(&Bs[srow][scol])     = *reinterpret_cast<const u16x8*>(gB + k0);
    *reinterpret_cast<u16x8*>(&Bs[srow][scol + 8]) = *reinterpret_cast<const u16x8*>(gB + k0 + 8);
    __syncthreads();
#pragma unroll
    for (int ks = 0; ks < BK; ks += 32) {
      bf16x8 a0 = *reinterpret_cast<const bf16x8*>(&As[wr      + lc][ks + lk]);
      bf16x8 a1 = *reinterpret_cast<const bf16x8*>(&As[wr + 16 + lc][ks + lk]);
      bf16x8 b0 = *reinterpret_cast<const bf16x8*>(&Bs[wc      + lc][ks + lk]);
      bf16x8 b1 = *reinterpret_cast<const bf16x8*>(&Bs[wc + 16 + lc][ks + lk]);
      acc[0][0] = __builtin_amdgcn_mfma_f32_16x16x32_bf16(a0, b0, acc[0][0], 0, 0, 0);
      acc[0][1] = __builtin_amdgcn_mfma_f32_16x16x32_bf16(a0, b1, acc[0][1], 0, 0, 0);
      acc[1][0] = __builtin_amdgcn_mfma_f32_16x16x32_bf16(a1, b0, acc[1][0], 0, 0, 0);
      acc[1][1] = __builtin_amdgcn_mfma_f32_16x16x32_bf16(a1, b1, acc[1][1], 0, 0, 0);
    }
    __syncthreads();
  }
  // C/D layout (verified): col = lane&15, row = (lane>>4)*4 + reg
#pragma unroll
  for (int fi = 0; fi < 2; ++fi)
#pragma unroll
    for (int fj = 0; fj < 2; ++fj) {
      const int col = n0 + wc + fj * 16 + lc;
      const float bv = bias[col];
      const int rbase = m0 + wr + fi * 16 + (l >> 4) * 4;
#pragma unroll
      for (int j = 0; j < 4; ++j)
        C[(size_t)(rbase + j) * Nn + col] = acc[fi][fj][j] + bv;
    }
}

// ---- grouped edge GEMM, W-resident-in-LDS variant ----
// One block per (group g, n-tile). B = W[wsel][n0:n0+64][0:512] loaded to LDS
// ONCE; loop over the bucket's edge m-tiles internally. W fetched exactly once
// per dispatch (20 MB total). A (gathered h rows) is cache-resident (8 MB).
__global__ __launch_bounds__(256) void k_edge(
    const u16* __restrict__ h, const u16* __restrict__ Wrel,
    const float* __restrict__ brel,
    const int* __restrict__ dep, const int* __restrict__ gov,
    const int* __restrict__ elist, const int* __restrict__ off,
    float* __restrict__ out)
{
  const int g = blockIdx.x;                 // 0..39
  const int n0 = blockIdx.y * BN;
  const int r = (g < NREL) ? g : g - NREL;
  const int base = off[r];
  const int cnt  = off[r + 1] - base;
  if (cnt <= 0) return;
  const bool fwd = (g < NREL);
  const int wsel = fwd ? r : NREL + r;
  const int* gsrc = fwd ? gov : dep;
  const int* gdst = fwd ? dep : gov;

  __shared__ u16 Bs[BN][DIM + LPAD];   // 64 x 520 u16 = 66560 B
  __shared__ u16 As[BM][BK + LPAD];    // 64 x 72  u16 =  9216 B
  __shared__ int s_src[BM];
  __shared__ int s_dst[BM];

  const int t = threadIdx.x;
  const int w = t >> 6, l = t & 63;
  const int wr = (w >> 1) * 32, wc = (w & 1) * 32;
  const int lc = l & 15, lk = (l >> 4) * 8;
  const int srow = t >> 2, scol = (t & 3) * 16;

  // stage full-K B slice once
  const u16* gB = Wrel + (size_t)wsel * DIM * DIM + (size_t)(n0 + srow) * DIM + scol;
  for (int kc = 0; kc < DIM; kc += BK) {
    *reinterpret_cast<u16x8*>(&Bs[srow][kc + scol])     = *reinterpret_cast<const u16x8*>(gB + kc);
    *reinterpret_cast<u16x8*>(&Bs[srow][kc + scol + 8]) = *reinterpret_cast<const u16x8*>(gB + kc + 8);
  }
  // hoist per-lane bias (2 output cols per lane)
  const float bv0 = brel[(size_t)wsel * DIM + n0 + wc + lc];
  const float bv1 = brel[(size_t)wsel * DIM + n0 + wc + 16 + lc];

  for (int m0 = 0; m0 < cnt; m0 += BM) {
    __syncthreads();   // prev epilogue done (s_dst reusable); also fences B load on iter 0
    const int mcnt = min(BM, cnt - m0);
    if (t < BM) {
      if (t < mcnt) {
        int e = elist[base + m0 + t];
        s_src[t] = gsrc[e];
        s_dst[t] = gdst[e];
      } else { s_src[t] = -1; s_dst[t] = -1; }
    }
    __syncthreads();

    const int arow = s_src[srow];
    const u16* gA = h + (size_t)arow * DIM + scol;

    f32x4 acc[2][2] = {};
    for (int k0 = 0; k0 < DIM; k0 += BK) {
      if (arow >= 0) {
        *reinterpret_cast<u16x8*>(&As[srow][scol])     = *reinterpret_cast<const u16x8*>(gA + k0);
        *reinterpret_cast<u16x8*>(&As[srow][scol + 8]) = *reinterpret_cast<const u16x8*>(gA + k0 + 8);
      } else {
        u16x8 z = {0,0,0,0,0,0,0,0};
        *reinterpret_cast<u16x8*>(&As[srow][scol]) = z;
        *reinterpret_cast<u16x8*>(&As[srow][scol + 8]) = z;
      }
      __syncthreads();
#pragma unroll
      for (int ks = 0; ks < BK; ks += 32) {
        bf16x8 a0 = *reinterpret_cast<const bf16x8*>(&As[wr      + lc][ks + lk]);
        bf16x8 a1 = *reinterpret_cast<const bf16x8*>(&As[wr + 16 + lc][ks + lk]);
        bf16x8 b0 = *reinterpret_cast<const bf16x8*>(&Bs[wc      + lc][k0 + ks + lk]);
        bf16x8 b1 = *reinterpret_cast<const bf16x8*>(&Bs[wc + 16 + lc][k0 + ks + lk]);
        acc[0][0] = __builtin_amdgcn_mfma_f32_16x16x32_bf16(a0, b0, acc[0][0], 0, 0, 0);
        acc[0][1] = __builtin_amdgcn_mfma_f32_16x16x32_bf16(a0, b1, acc[0][1], 0, 0, 0);
        acc[1][0] = __builtin_amdgcn_mfma_f32_16x16x32_bf16(a1, b0, acc[1][0], 0, 0, 0);
        acc[1][1] = __builtin_amdgcn_mfma_f32_16x16x32_bf16(a1, b1, acc[1][1], 0, 0, 0);
      }
      __syncthreads();
    }

#pragma unroll
    for (int fi = 0; fi < 2; ++fi)
#pragma unroll
      for (int fj = 0; fj < 2; ++fj) {
        const int col = n0 + wc + fj * 16 + lc;
        const float bv = fj ? bv1 : bv0;
        const int rbase = wr + fi * 16 + (l >> 4) * 4;
#pragma unroll
        for (int j = 0; j < 4; ++j) {
          const int mrow = rbase + j;
          if (mrow < mcnt) {
            const int dst = s_dst[mrow];
            unsafeAtomicAdd(&out[(size_t)dst * DIM + col], acc[fi][fj][j] + bv);
          }
        }
      }
  }
}

extern "C" void kernel_launch(void* const* d_in, const int* in_sizes, int n_in,
                              void* d_out, int out_size, void* d_ws, size_t ws_size,
                              hipStream_t stream) {
  const float* x      = (const float*)d_in[0];
  const int*   dep    = (const int*)d_in[1];
  const int*   rel    = (const int*)d_in[2];
  const int*   gov    = (const int*)d_in[3];
  const float* W_self = (const float*)d_in[4];
  const float* b_self = (const float*)d_in[5];
  const float* W_rel  = (const float*)d_in[6];
  const float* b_rel  = (const float*)d_in[7];
  const float* W_ff   = (const float*)d_in[8];
  const float* b_ff   = (const float*)d_in[9];
  float* out = (float*)d_out;

  char* ws = (char*)d_ws;
  size_t o = 0;
  auto alloc = [&](size_t bytes) -> void* {
    void* p = ws + o;
    o = (o + bytes + 255) & ~(size_t)255;
    return p;
  };
  u16*   Wrel_bf  = (u16*)alloc((size_t)2 * NGRP * DIM * DIM * 2);
  u16*   Wself_bf = (u16*)alloc((size_t)2 * DIM * DIM * 2);
  u16*   Wff_bf   = (u16*)alloc((size_t)OUTD * DIM * 2);
  u16*   hbuf     = (u16*)alloc((size_t)N_TOK * DIM * 2);
  float* outf     = (float*)alloc((size_t)N_TOK * DIM * 4);
  int*   cnt      = (int*)alloc(NREL * 4);
  int*   offs     = (int*)alloc((NREL + 1) * 4);
  int*   cur      = (int*)alloc(NREL * 4);
  int*   elist    = (int*)alloc(N_TOK * 4);
  (void)ws_size; (void)in_sizes; (void)n_in; (void)out_size;

  // weights -> bf16
  k_cvt<<<2048, 256, 0, stream>>>(W_rel,  Wrel_bf,  2 * NGRP * DIM * DIM / 4, 0);
  k_cvt<<<512,  256, 0, stream>>>(W_self, Wself_bf, 2 * DIM * DIM / 4, 0);
  k_cvt<<<128,  256, 0, stream>>>(W_ff,   Wff_bf,   OUTD * DIM / 4, 0);

  // bucket edges by relation
  hipMemsetAsync(cnt, 0, NREL * 4, stream);
  hipMemsetAsync(cur, 0, NREL * 4, stream);
  k_hist<<<N_TOK / 256, 256, 0, stream>>>(rel, cnt);
  k_scan<<<1, 64, 0, stream>>>(cnt, offs);
  k_fill<<<N_TOK / 256, 256, 0, stream>>>(rel, offs, cur, elist);

  // h0 = bf16(x)
  k_cvt<<<2048, 256, 0, stream>>>(x, hbuf, N_TOK * DIM / 4, 0);

  for (int l = 0; l < 2; ++l) {
    const u16*   Ws = Wself_bf + (size_t)l * DIM * DIM;
    const float* bs = b_self + (size_t)l * DIM;
    const u16*   Wr = Wrel_bf + (size_t)l * NGRP * DIM * DIM;
    const float* br = b_rel + (size_t)l * NGRP * DIM;

    dim3 g1(N_TOK / BM, DIM / BN);
    k_gemm<<<g1, 256, 0, stream>>>(hbuf, Ws, bs, outf, N_TOK, DIM);

    dim3 g2(NGRP, DIM / BN);   // one block per (group, n-tile); m-loop inside
    k_edge<<<g2, 256, 0, stream>>>(hbuf, Wr, br, dep, gov, elist, offs, outf);

    // h_{l+1} = bf16(relu(out))
    k_cvt<<<2048, 256, 0, stream>>>(outf, hbuf, N_TOK * DIM / 4, 1);
  }

  dim3 g3(N_TOK / BM, OUTD / BN);
  k_gemm<<<g3, 256, 0, stream>>>(hbuf, Wff_bf, b_ff, out, N_TOK, OUTD);
}